// Round 5
// baseline (631.534 us; speedup 1.0000x reference)
//
#include <hip/hip_runtime.h>
#include <math.h>

// Problem constants
#define NB   64
#define CC   256
#define TT   64
#define VV   25
#define HID  16
#define NG   5
#define ROWF 1600          // floats per (n,c) pair = T*V
#define ROWF4 400          // float4 per (n,c) pair
#define PAIRS 2            // (n,c) pairs per apply block (12.8 KB LDS -> 8 blocks/CU)

// torso joints {0,1,2,3,20} as a bitmask
#define TORSO_MASK 0x10000Fu

// native vector type accepted by __builtin_nontemporal_store
typedef float fx4 __attribute__((ext_vector_type(4)));

// output joint position -> source joint (concat order: TORSO, LH, LL, RH, RL)
// packed LUT: src | (grp<<8)
__constant__ int PERM_LUT[VV] = {
    0|(0<<8), 1|(0<<8), 2|(0<<8), 3|(0<<8), 20|(0<<8),
    8|(1<<8), 9|(1<<8), 10|(1<<8), 11|(1<<8), 23|(1<<8), 24|(1<<8),
    16|(2<<8), 17|(2<<8), 18|(2<<8), 19|(2<<8),
    4|(3<<8), 5|(3<<8), 6|(3<<8), 7|(3<<8), 21|(3<<8), 22|(3<<8),
    12|(4<<8), 13|(4<<8), 14|(4<<8), 15|(4<<8)
};

// Completion counters for the last-block gates pattern.
// Zero-initialized at module load; the last block of each n resets its counter
// to 0 (atomicExch) before computing gates, so every iteration / graph replay
// starts from 0. Lives outside the harness-poisoned workspace.
__device__ int g_cnt[NB];

// ---------------- Kernel A: torso pooling + last-block gate MLP ----------------
// One wave per (n,c) pair; 4 waves per block; 4096 blocks. All 4 pairs of a
// block share the same n (4 divides CC). After a block's pools are globally
// visible, it increments g_cnt[n]; the 64th (last) block for that n computes
// the gate MLP for all 256 channels of n inline (identical math to the old
// gates_kernel), overlapped with the tail of other blocks' pooling.
__global__ __launch_bounds__(256)
void pool_gates_kernel(const float4* __restrict__ x4,
                       float* __restrict__ avg_g,       // (N,C)
                       float* __restrict__ max_g,       // (N,C)
                       const float* __restrict__ W1s,   // (5,16,256)
                       const float* __restrict__ b1s,   // (5,16)
                       const float* __restrict__ W2s,   // (5,256,16)
                       const float* __restrict__ b2s,   // (5,256)
                       float* __restrict__ gates) {     // (N,5,256)
    __shared__ float4 sAvg[CC / 4];
    __shared__ float4 sMax[CC / 4];
    __shared__ float  sHA[NG * HID];
    __shared__ float  sHM[NG * HID];
    __shared__ int    sLast;

    const int tid  = threadIdx.x;
    const int wave = tid >> 6;
    const int lane = tid & 63;
    const int pair = blockIdx.x * 4 + wave;      // n*C + c
    const int n    = (blockIdx.x * 4) >> 8;      // same n for all 4 waves
    const int base4 = pair * ROWF4;

    // ---- pooling (verified round-4 code) ----
    const unsigned long long M2 = (unsigned long long)TORSO_MASK
                                | ((unsigned long long)TORSO_MASK << 25);
    const float NEG = -3.4e38f;
    float s = 0.0f;
    float m = NEG;
    for (int i = lane; i < ROWF4; i += 64) {
        float4 v = x4[base4 + i];
        const int j = (4 * i) % 25;              // joint of first element
        const unsigned bits = (unsigned)((M2 >> j) & 0xFULL);
        s += (bits & 1u) ? v.x : 0.0f;
        s += (bits & 2u) ? v.y : 0.0f;
        s += (bits & 4u) ? v.z : 0.0f;
        s += (bits & 8u) ? v.w : 0.0f;
        m = fmaxf(m, (bits & 1u) ? v.x : NEG);
        m = fmaxf(m, (bits & 2u) ? v.y : NEG);
        m = fmaxf(m, (bits & 4u) ? v.z : NEG);
        m = fmaxf(m, (bits & 8u) ? v.w : NEG);
    }
    #pragma unroll
    for (int off = 32; off >= 1; off >>= 1) {
        s += __shfl_xor(s, off, 64);
        m = fmaxf(m, __shfl_xor(m, off, 64));
    }
    if (lane == 0) {
        avg_g[pair] = s * (1.0f / (TT * 5));
        max_g[pair] = m;
    }

    // ---- last-block election (hipCUB device-reduce pattern) ----
    __threadfence();                 // release our avg/max to device scope
    __syncthreads();                 // all 4 waves' stores + fences done
    if (tid == 0) {
        const int old = atomicAdd(&g_cnt[n], 1);
        sLast = (old == 63);
        if (old == 63) atomicExch(&g_cnt[n], 0);   // self-reset for next iter
    }
    __syncthreads();
    if (!sLast) return;

    __threadfence();                 // acquire: invalidate stale cached avg/max

    // ---- gate MLP for this n (identical math to the old gates_kernel) ----
    if (tid < 64)       sAvg[tid]      = reinterpret_cast<const float4*>(avg_g + n * CC)[tid];
    else if (tid < 128) sMax[tid - 64] = reinterpret_cast<const float4*>(max_g + n * CC)[tid - 64];
    __syncthreads();

    if (tid < 2 * NG * HID) {              // 160 threads
        const int type = tid / (NG * HID); // 0 = avg, 1 = max
        const int rem  = tid % (NG * HID); // f*16 + j
        const float4* p = type ? sMax : sAvg;
        const float4* w = reinterpret_cast<const float4*>(W1s + rem * CC);
        float h = b1s[rem];
        #pragma unroll 8
        for (int c4 = 0; c4 < CC / 4; ++c4) {
            float4 a = w[c4], b = p[c4];
            h += a.x * b.x + a.y * b.y + a.z * b.z + a.w * b.w;
        }
        h = fmaxf(h, 0.0f);
        if (type) sHM[rem] = h; else sHA[rem] = h;
    }
    __syncthreads();

    const int c = tid;
    #pragma unroll
    for (int f = 0; f < NG; ++f) {
        const float4* w2 = reinterpret_cast<const float4*>(W2s + (f * CC + c) * HID);
        float g = 2.0f * b2s[f * CC + c];
        #pragma unroll
        for (int j4 = 0; j4 < HID / 4; ++j4) {
            float4 w = w2[j4];
            const int jb = f * HID + j4 * 4;
            g += w.x * (sHA[jb + 0] + sHM[jb + 0]);
            g += w.y * (sHA[jb + 1] + sHM[jb + 1]);
            g += w.z * (sHA[jb + 2] + sHM[jb + 2]);
            g += w.w * (sHA[jb + 3] + sHM[jb + 3]);
        }
        gates[(n * NG + f) * CC + c] = 1.0f / (1.0f + expf(-g));
    }
}

// ---------------- Kernel B: LDS-staged scale + joint permutation ----------------
// PAIRS=2 pairs per 256-thread block: 12.8 KB LDS -> 8 blocks/CU.
// Nontemporal output stores keep the 103 MB write stream from evicting
// L3-resident x (warmed by pool_gates_kernel).
__global__ __launch_bounds__(256)
void apply_kernel(const float4* __restrict__ x4,
                  const float* __restrict__ gates,
                  fx4* __restrict__ out4) {
    __shared__ float lds[PAIRS * ROWF];
    __shared__ float sg[PAIRS * NG];
    __shared__ int sLut[VV];

    const int tid = threadIdx.x;
    const int nc0 = blockIdx.x * PAIRS;
    const int base4 = nc0 * ROWF4;

    #pragma unroll
    for (int i = tid; i < PAIRS * ROWF4; i += 256) {
        reinterpret_cast<float4*>(lds)[i] = x4[base4 + i];
    }
    if (tid < PAIRS * NG) {                 // 10 gate values
        const int q = tid / NG, f = tid % NG;
        const int nc = nc0 + q;
        sg[tid] = gates[((nc >> 8) * NG + f) * CC + (nc & (CC - 1))];
    }
    if (tid < VV) sLut[tid] = PERM_LUT[tid];
    __syncthreads();

    #pragma unroll
    for (int i = tid; i < PAIRS * ROWF4; i += 256) {
        const int q = i / ROWF4;
        const int e0 = 4 * (i - q * ROWF4);   // first element index within pair
        int row = e0 / 25;
        int p   = e0 - row * 25;
        const float* lrow = lds + q * ROWF;
        const float* gq   = sg + q * NG;
        fx4 r;
        #pragma unroll
        for (int k = 0; k < 4; ++k) {
            const int lut = sLut[p];
            r[k] = lrow[row * 25 + (lut & 0xFF)] * gq[lut >> 8];
            ++p;
            if (p >= 25) { p = 0; ++row; }
        }
        __builtin_nontemporal_store(r, &out4[base4 + i]);
    }
}

extern "C" void kernel_launch(void* const* d_in, const int* in_sizes, int n_in,
                              void* d_out, int out_size, void* d_ws, size_t ws_size,
                              hipStream_t stream) {
    const float* x   = (const float*)d_in[0];
    const float* W1s = (const float*)d_in[1];
    const float* b1s = (const float*)d_in[2];
    const float* W2s = (const float*)d_in[3];
    const float* b2s = (const float*)d_in[4];

    float* avg   = (float*)d_ws;                  // N*C
    float* mx    = avg + NB * CC;                 // N*C
    float* gates = mx + NB * CC;                  // N*5*C

    // Kernel A: pooling + last-block gate MLP (one wave per (n,c), 4096 blocks)
    pool_gates_kernel<<<(NB * CC) / 4, 256, 0, stream>>>(
        (const float4*)x, avg, mx, W1s, b1s, W2s, b2s, gates);

    // Kernel B: PAIRS (n,c) pairs per block, 8192 blocks
    apply_kernel<<<(NB * CC) / PAIRS, 256, 0, stream>>>(
        (const float4*)x, gates, (fx4*)d_out);
}

// Round 6
// 251.028 us; speedup vs baseline: 2.5158x; 2.5158x over previous
//
#include <hip/hip_runtime.h>
#include <math.h>

// Problem constants
#define NB   64
#define CC   256
#define TT   64
#define VV   25
#define HID  16
#define NG   5
#define ROWF 1600          // floats per (n,c) pair = T*V
#define ROWF4 400          // float4 per (n,c) pair
#define PAIRS 2            // (n,c) pairs per apply block (12.8 KB LDS -> 8 blocks/CU)

// torso joints {0,1,2,3,20} as a bitmask
#define TORSO_MASK 0x10000Fu

// native vector type accepted by __builtin_nontemporal_store
typedef float fx4 __attribute__((ext_vector_type(4)));

// output joint position -> source joint (concat order: TORSO, LH, LL, RH, RL)
// packed LUT: src | (grp<<8)
__constant__ int PERM_LUT[VV] = {
    0|(0<<8), 1|(0<<8), 2|(0<<8), 3|(0<<8), 20|(0<<8),
    8|(1<<8), 9|(1<<8), 10|(1<<8), 11|(1<<8), 23|(1<<8), 24|(1<<8),
    16|(2<<8), 17|(2<<8), 18|(2<<8), 19|(2<<8),
    4|(3<<8), 5|(3<<8), 6|(3<<8), 7|(3<<8), 21|(3<<8), 22|(3<<8),
    12|(4<<8), 13|(4<<8), 14|(4<<8), 15|(4<<8)
};

// Completion counters for the last-block gates pattern (round-5 proved this
// election + self-reset correct under graph replay). Zero-init at module load;
// last block resets its counter so every iteration starts from 0.
__device__ int g_cnt[NB];

// ---------------- Kernel A: torso pooling + last-block gate MLP ----------------
// One wave per (n,c) pair; 4 waves per block; 4096 blocks; all 4 pairs share n.
// Coherence WITHOUT cache-maintenance ops (round-5's __threadfence was the
// 500us killer): avg/max are published with device-scope atomicExch (lands at
// the die-level L3, visible to all XCDs; does not populate L2). __syncthreads
// drains vmcnt in every wave, so all publishes are complete before the counter
// increment. The last block's plain loads cannot see stale data: caches were
// invalidated at dispatch start and no block populates L2 with these lines.
__global__ __launch_bounds__(256)
void pool_gates_kernel(const float4* __restrict__ x4,
                       float* __restrict__ avg_g,       // (N,C)
                       float* __restrict__ max_g,       // (N,C)
                       const float* __restrict__ W1s,   // (5,16,256)
                       const float* __restrict__ b1s,   // (5,16)
                       const float* __restrict__ W2s,   // (5,256,16)
                       const float* __restrict__ b2s,   // (5,256)
                       float* __restrict__ gates) {     // (N,5,256)
    __shared__ float4 sAvg[CC / 4];
    __shared__ float4 sMax[CC / 4];
    __shared__ float  sHA[NG * HID];
    __shared__ float  sHM[NG * HID];
    __shared__ int    sLast;

    const int tid  = threadIdx.x;
    const int wave = tid >> 6;
    const int lane = tid & 63;
    const int pair = blockIdx.x * 4 + wave;      // n*C + c
    const int n    = (blockIdx.x * 4) >> 8;      // same n for all 4 waves
    const int base4 = pair * ROWF4;

    // ---- pooling (round-4 verified code) ----
    const unsigned long long M2 = (unsigned long long)TORSO_MASK
                                | ((unsigned long long)TORSO_MASK << 25);
    const float NEG = -3.4e38f;
    float s = 0.0f;
    float m = NEG;
    for (int i = lane; i < ROWF4; i += 64) {
        float4 v = x4[base4 + i];
        const int j = (4 * i) % 25;              // joint of first element
        const unsigned bits = (unsigned)((M2 >> j) & 0xFULL);
        s += (bits & 1u) ? v.x : 0.0f;
        s += (bits & 2u) ? v.y : 0.0f;
        s += (bits & 4u) ? v.z : 0.0f;
        s += (bits & 8u) ? v.w : 0.0f;
        m = fmaxf(m, (bits & 1u) ? v.x : NEG);
        m = fmaxf(m, (bits & 2u) ? v.y : NEG);
        m = fmaxf(m, (bits & 4u) ? v.z : NEG);
        m = fmaxf(m, (bits & 8u) ? v.w : NEG);
    }
    #pragma unroll
    for (int off = 32; off >= 1; off >>= 1) {
        s += __shfl_xor(s, off, 64);
        m = fmaxf(m, __shfl_xor(m, off, 64));
    }
    if (lane == 0) {
        // publish via device-scope atomics: coherent at L3, no cache ops
        atomicExch(&avg_g[pair], s * (1.0f / (TT * 5)));
        atomicExch(&max_g[pair], m);
    }

    // ---- last-block election (no threadfence; syncthreads drains vmcnt) ----
    __syncthreads();                 // all 4 waves' atomicExch complete (vmcnt 0)
    if (tid == 0) {
        const int old = atomicAdd(&g_cnt[n], 1);
        sLast = (old == 63);
        if (old == 63) atomicExch(&g_cnt[n], 0);   // self-reset for next iter
    }
    __syncthreads();
    if (!sLast) return;

    // ---- gate MLP for this n (round-4 verified gates code) ----
    if (tid < 64)       sAvg[tid]      = reinterpret_cast<const float4*>(avg_g + n * CC)[tid];
    else if (tid < 128) sMax[tid - 64] = reinterpret_cast<const float4*>(max_g + n * CC)[tid - 64];
    __syncthreads();

    if (tid < 2 * NG * HID) {              // 160 threads
        const int type = tid / (NG * HID); // 0 = avg, 1 = max
        const int rem  = tid % (NG * HID); // f*16 + j
        const float4* p = type ? sMax : sAvg;
        const float4* w = reinterpret_cast<const float4*>(W1s + rem * CC);
        float h = b1s[rem];
        #pragma unroll 8
        for (int c4 = 0; c4 < CC / 4; ++c4) {
            float4 a = w[c4], b = p[c4];
            h += a.x * b.x + a.y * b.y + a.z * b.z + a.w * b.w;
        }
        h = fmaxf(h, 0.0f);
        if (type) sHM[rem] = h; else sHA[rem] = h;
    }
    __syncthreads();

    const int c = tid;
    #pragma unroll
    for (int f = 0; f < NG; ++f) {
        const float4* w2 = reinterpret_cast<const float4*>(W2s + (f * CC + c) * HID);
        float g = 2.0f * b2s[f * CC + c];
        #pragma unroll
        for (int j4 = 0; j4 < HID / 4; ++j4) {
            float4 w = w2[j4];
            const int jb = f * HID + j4 * 4;
            g += w.x * (sHA[jb + 0] + sHM[jb + 0]);
            g += w.y * (sHA[jb + 1] + sHM[jb + 1]);
            g += w.z * (sHA[jb + 2] + sHM[jb + 2]);
            g += w.w * (sHA[jb + 3] + sHM[jb + 3]);
        }
        gates[(n * NG + f) * CC + c] = 1.0f / (1.0f + expf(-g));
    }
}

// ---------------- Kernel B: LDS-staged scale + joint permutation ----------------
// PAIRS=2 pairs per 256-thread block: 12.8 KB LDS -> 8 blocks/CU.
// Nontemporal output stores keep the 103 MB write stream from evicting
// L3-resident x (warmed by pool_gates_kernel).
__global__ __launch_bounds__(256)
void apply_kernel(const float4* __restrict__ x4,
                  const float* __restrict__ gates,
                  fx4* __restrict__ out4) {
    __shared__ float lds[PAIRS * ROWF];
    __shared__ float sg[PAIRS * NG];
    __shared__ int sLut[VV];

    const int tid = threadIdx.x;
    const int nc0 = blockIdx.x * PAIRS;
    const int base4 = nc0 * ROWF4;

    #pragma unroll
    for (int i = tid; i < PAIRS * ROWF4; i += 256) {
        reinterpret_cast<float4*>(lds)[i] = x4[base4 + i];
    }
    if (tid < PAIRS * NG) {                 // 10 gate values
        const int q = tid / NG, f = tid % NG;
        const int nc = nc0 + q;
        sg[tid] = gates[((nc >> 8) * NG + f) * CC + (nc & (CC - 1))];
    }
    if (tid < VV) sLut[tid] = PERM_LUT[tid];
    __syncthreads();

    #pragma unroll
    for (int i = tid; i < PAIRS * ROWF4; i += 256) {
        const int q = i / ROWF4;
        const int e0 = 4 * (i - q * ROWF4);   // first element index within pair
        int row = e0 / 25;
        int p   = e0 - row * 25;
        const float* lrow = lds + q * ROWF;
        const float* gq   = sg + q * NG;
        fx4 r;
        #pragma unroll
        for (int k = 0; k < 4; ++k) {
            const int lut = sLut[p];
            r[k] = lrow[row * 25 + (lut & 0xFF)] * gq[lut >> 8];
            ++p;
            if (p >= 25) { p = 0; ++row; }
        }
        __builtin_nontemporal_store(r, &out4[base4 + i]);
    }
}

extern "C" void kernel_launch(void* const* d_in, const int* in_sizes, int n_in,
                              void* d_out, int out_size, void* d_ws, size_t ws_size,
                              hipStream_t stream) {
    const float* x   = (const float*)d_in[0];
    const float* W1s = (const float*)d_in[1];
    const float* b1s = (const float*)d_in[2];
    const float* W2s = (const float*)d_in[3];
    const float* b2s = (const float*)d_in[4];

    float* avg   = (float*)d_ws;                  // N*C
    float* mx    = avg + NB * CC;                 // N*C
    float* gates = mx + NB * CC;                  // N*5*C

    // Kernel A: pooling + last-block gate MLP (one wave per (n,c), 4096 blocks)
    pool_gates_kernel<<<(NB * CC) / 4, 256, 0, stream>>>(
        (const float4*)x, avg, mx, W1s, b1s, W2s, b2s, gates);

    // Kernel B: PAIRS (n,c) pairs per block, 8192 blocks
    apply_kernel<<<(NB * CC) / PAIRS, 256, 0, stream>>>(
        (const float4*)x, gates, (fx4*)d_out);
}

// Round 7
// 217.709 us; speedup vs baseline: 2.9008x; 1.1530x over previous
//
#include <hip/hip_runtime.h>
#include <math.h>

// Problem constants
#define NB   64
#define CC   256
#define TT   64
#define VV   25
#define HID  16
#define NG   5
#define ROWF 1600          // floats per (n,c) pair = T*V
#define ROWF4 400          // float4 per (n,c) pair
#define PAIRS 2            // (n,c) pairs per apply block (12.8 KB LDS -> 8 blocks/CU)

// torso joints {0,1,2,3,20} as a bitmask
#define TORSO_MASK 0x10000Fu

// native vector type accepted by __builtin_nontemporal_store
typedef float fx4 __attribute__((ext_vector_type(4)));

// output joint position -> source joint (concat order: TORSO, LH, LL, RH, RL)
// packed LUT: src | (grp<<8)
__constant__ int PERM_LUT[VV] = {
    0|(0<<8), 1|(0<<8), 2|(0<<8), 3|(0<<8), 20|(0<<8),
    8|(1<<8), 9|(1<<8), 10|(1<<8), 11|(1<<8), 23|(1<<8), 24|(1<<8),
    16|(2<<8), 17|(2<<8), 18|(2<<8), 19|(2<<8),
    4|(3<<8), 5|(3<<8), 6|(3<<8), 7|(3<<8), 21|(3<<8), 22|(3<<8),
    12|(4<<8), 13|(4<<8), 14|(4<<8), 15|(4<<8)
};

// ---------------- Kernel A: torso pooling, coalesced float4, branchless ----------------
// One wave per (n,c) pair; 4 waves per block; 4096 blocks.
__global__ void pool_kernel(const float4* __restrict__ x4,
                            float* __restrict__ avg_out,
                            float* __restrict__ max_out) {
    const int wave = threadIdx.x >> 6;
    const int lane = threadIdx.x & 63;
    const int pair = blockIdx.x * 4 + wave;      // n*C + c
    const int base4 = pair * ROWF4;

    // 50-bit replicated torso mask handles the joint wrap within a float4
    const unsigned long long M2 = (unsigned long long)TORSO_MASK
                                | ((unsigned long long)TORSO_MASK << 25);
    const float NEG = -3.4e38f;
    float s = 0.0f;
    float m = NEG;
    for (int i = lane; i < ROWF4; i += 64) {
        float4 v = x4[base4 + i];
        const int j = (4 * i) % 25;              // joint of first element
        const unsigned bits = (unsigned)((M2 >> j) & 0xFULL);
        // branchless: cndmask + add/max, no exec-mask toggling
        s += (bits & 1u) ? v.x : 0.0f;
        s += (bits & 2u) ? v.y : 0.0f;
        s += (bits & 4u) ? v.z : 0.0f;
        s += (bits & 8u) ? v.w : 0.0f;
        m = fmaxf(m, (bits & 1u) ? v.x : NEG);
        m = fmaxf(m, (bits & 2u) ? v.y : NEG);
        m = fmaxf(m, (bits & 4u) ? v.z : NEG);
        m = fmaxf(m, (bits & 8u) ? v.w : NEG);
    }
    #pragma unroll
    for (int off = 32; off >= 1; off >>= 1) {
        s += __shfl_xor(s, off, 64);
        m = fmaxf(m, __shfl_xor(m, off, 64));
    }
    if (lane == 0) {
        avg_out[pair] = s * (1.0f / (TT * 5));
        max_out[pair] = m;
    }
}

// ---------------- Kernel B: gate MLPs (one block per n, 64 blocks) ----------------
__global__ void gates_kernel(const float* __restrict__ avg_in,
                             const float* __restrict__ max_in,
                             const float* __restrict__ W1s,   // (5,16,256)
                             const float* __restrict__ b1s,   // (5,16)
                             const float* __restrict__ W2s,   // (5,256,16)
                             const float* __restrict__ b2s,   // (5,256)
                             float* __restrict__ gates) {     // (N,5,256)
    __shared__ float4 sAvg[CC / 4];
    __shared__ float4 sMax[CC / 4];
    __shared__ float sHA[NG * HID];
    __shared__ float sHM[NG * HID];

    const int n = blockIdx.x;
    const int tid = threadIdx.x;

    if (tid < 64)       sAvg[tid]      = reinterpret_cast<const float4*>(avg_in + n * CC)[tid];
    else if (tid < 128) sMax[tid - 64] = reinterpret_cast<const float4*>(max_in + n * CC)[tid - 64];
    __syncthreads();

    if (tid < 2 * NG * HID) {              // 160 threads
        const int type = tid / (NG * HID); // 0 = avg, 1 = max
        const int rem  = tid % (NG * HID); // f*16 + j
        const float4* p = type ? sMax : sAvg;
        const float4* w = reinterpret_cast<const float4*>(W1s + rem * CC);
        float h = b1s[rem];
        #pragma unroll 8
        for (int c4 = 0; c4 < CC / 4; ++c4) {
            float4 a = w[c4], b = p[c4];
            h += a.x * b.x + a.y * b.y + a.z * b.z + a.w * b.w;
        }
        h = fmaxf(h, 0.0f);
        if (type) sHM[rem] = h; else sHA[rem] = h;
    }
    __syncthreads();

    const int c = tid;
    #pragma unroll
    for (int f = 0; f < NG; ++f) {
        const float4* w2 = reinterpret_cast<const float4*>(W2s + (f * CC + c) * HID);
        float g = 2.0f * b2s[f * CC + c];
        #pragma unroll
        for (int j4 = 0; j4 < HID / 4; ++j4) {
            float4 w = w2[j4];
            const int jb = f * HID + j4 * 4;
            g += w.x * (sHA[jb + 0] + sHM[jb + 0]);
            g += w.y * (sHA[jb + 1] + sHM[jb + 1]);
            g += w.z * (sHA[jb + 2] + sHM[jb + 2]);
            g += w.w * (sHA[jb + 3] + sHM[jb + 3]);
        }
        gates[(n * NG + f) * CC + c] = 1.0f / (1.0f + expf(-g));
    }
}

// ---------------- Kernel C: LDS-staged scale + joint permutation ----------------
// PAIRS=2 pairs per 256-thread block: 12.8 KB LDS -> 8 blocks/CU (32-wave cap).
// Output uses nontemporal stores so the 103 MB write stream does not evict the
// L3-resident x (warmed by pool_kernel).
__global__ __launch_bounds__(256)
void apply_kernel(const float4* __restrict__ x4,
                  const float* __restrict__ gates,
                  fx4* __restrict__ out4) {
    __shared__ float lds[PAIRS * ROWF];
    __shared__ float sg[PAIRS * NG];
    __shared__ int sLut[VV];

    const int tid = threadIdx.x;
    const int nc0 = blockIdx.x * PAIRS;
    const int base4 = nc0 * ROWF4;

    #pragma unroll
    for (int i = tid; i < PAIRS * ROWF4; i += 256) {
        reinterpret_cast<float4*>(lds)[i] = x4[base4 + i];
    }
    if (tid < PAIRS * NG) {                 // 10 gate values
        const int q = tid / NG, f = tid % NG;
        const int nc = nc0 + q;
        sg[tid] = gates[((nc >> 8) * NG + f) * CC + (nc & (CC - 1))];
    }
    if (tid < VV) sLut[tid] = PERM_LUT[tid];
    __syncthreads();

    #pragma unroll
    for (int i = tid; i < PAIRS * ROWF4; i += 256) {
        const int q = i / ROWF4;
        const int e0 = 4 * (i - q * ROWF4);   // first element index within pair
        int row = e0 / 25;
        int p   = e0 - row * 25;
        const float* lrow = lds + q * ROWF;
        const float* gq   = sg + q * NG;
        fx4 r;
        #pragma unroll
        for (int k = 0; k < 4; ++k) {
            const int lut = sLut[p];
            r[k] = lrow[row * 25 + (lut & 0xFF)] * gq[lut >> 8];
            ++p;
            if (p >= 25) { p = 0; ++row; }
        }
        __builtin_nontemporal_store(r, &out4[base4 + i]);
    }
}

extern "C" void kernel_launch(void* const* d_in, const int* in_sizes, int n_in,
                              void* d_out, int out_size, void* d_ws, size_t ws_size,
                              hipStream_t stream) {
    const float* x   = (const float*)d_in[0];
    const float* W1s = (const float*)d_in[1];
    const float* b1s = (const float*)d_in[2];
    const float* W2s = (const float*)d_in[3];
    const float* b2s = (const float*)d_in[4];

    float* avg   = (float*)d_ws;                  // N*C
    float* mx    = avg + NB * CC;                 // N*C
    float* gates = mx + NB * CC;                  // N*5*C

    // Kernel A: one wave per (n,c), 4 waves/block
    pool_kernel<<<(NB * CC) / 4, 256, 0, stream>>>(
        (const float4*)x, avg, mx);

    // Kernel B: one block per n
    gates_kernel<<<NB, CC, 0, stream>>>(avg, mx, W1s, b1s, W2s, b2s, gates);

    // Kernel C: PAIRS (n,c) pairs per block, 8192 blocks
    apply_kernel<<<(NB * CC) / PAIRS, 256, 0, stream>>>(
        (const float4*)x, gates, (fx4*)d_out);
}